// Round 6
// baseline (358.405 us; speedup 1.0000x reference)
//
#include <hip/hip_runtime.h>

typedef unsigned short ushort_t;
typedef __attribute__((ext_vector_type(8))) short s16x8;   // 8 bf16 (4 VGPRs) MFMA A/B frag
typedef __attribute__((ext_vector_type(4))) float f32x4;   // 4 f32 MFMA C/D frag

#define B_PATHS 8192
#define NSTEP   30
#define DD      100
#define HH      110
#define TT      29            // number of subnets
#define ROWSTR  3000          // NSTEP*DD floats per path
#define LDK     136           // padded k-stride (bf16 elems) for act tiles; 272B rows
#define WFRAGSZ 14336         // per-stage frag-ordered W: 4 kb * 7 nt * 64 lanes * 8 elems
#define DT_C    (1.0f/30.0f)
#define R_C     0.05f
#define EPS_C   1e-3f

// workspace offsets (bytes)
#define WS_WPREP 0u
#define WS_BPREP 2494464u
#define WS_SBUF  2539008u
#define WS_XBT   3522048u                 // 29*8192*128*2 = 60,817,408
#define WS_PBUF  64339456u                // 30*8192*100*2 = 49,152,000  (end 113,491,456)

__device__ __forceinline__ ushort_t f2bf(float f) {  // RNE f32->bf16
  unsigned u = __float_as_uint(f);
  u = u + 0x7FFFu + ((u >> 16) & 1u);
  return (ushort_t)(u >> 16);
}
__device__ __forceinline__ float bf2f(ushort_t u) {
  return __uint_as_float(((unsigned)u) << 16);
}

// ---------------------------------------------------------------------------
// Prep: fold BN into weights/biases; emit W in MFMA B-fragment order:
//   elem j of chunk c=((kb*7+nt)*64+lane):  B[n=nt*16+(lane&15)][k=kb*32+(lane>>4)*8+j]
// ---------------------------------------------------------------------------
__global__ void prep_kernel(const float* __restrict__ W1, const float* __restrict__ W2,
                            const float* __restrict__ W3,
                            const float* g0, const float* b0, const float* m0, const float* v0,
                            const float* g1, const float* b1, const float* m1, const float* v1,
                            const float* g2, const float* b2, const float* m2, const float* v2,
                            const float* g3, const float* b3, const float* m3, const float* v3,
                            ushort_t* __restrict__ wprep, float* __restrict__ bprep)
{
  const int mat = blockIdx.x, t = blockIdx.y, tid = threadIdx.x;
  __shared__ __align__(16) float wsh[110*110];
  __shared__ float sin_[112], hin_[112], sout_[112], hout_[112];

  int Kr, Nr; const float* W; const float *g, *bb, *mm, *vv;
  if (mat == 0)      { Kr = 100; Nr = 110; W = W1 + t*11000; g = g0+t*100; bb = b0+t*100; mm = m0+t*100; vv = v0+t*100; }
  else if (mat == 1) { Kr = 110; Nr = 110; W = W2 + t*12100; g = g1+t*110; bb = b1+t*110; mm = m1+t*110; vv = v1+t*110; }
  else               { Kr = 110; Nr = 100; W = W3 + t*11000; g = g2+t*110; bb = b2+t*110; mm = m2+t*110; vv = v2+t*110; }

  if (tid < Kr) {
    float s = g[tid] * rsqrtf(vv[tid] + EPS_C);
    sin_[tid] = s; hin_[tid] = bb[tid] - mm[tid]*s;
  }
  if (mat == 2 && tid < Nr) {
    float s = g3[t*100+tid] * rsqrtf(v3[t*100+tid] + EPS_C);
    sout_[tid] = s; hout_[tid] = b3[t*100+tid] - m3[t*100+tid]*s;
  }
  {
    const int n4 = (Kr*Nr) >> 2;
    for (int i = tid; i < n4; i += 256)
      ((float4*)wsh)[i] = ((const float4*)W)[i];
  }
  __syncthreads();

  if (tid < 128) {
    float c = 0.f;
    if (tid < Nr) {
      for (int k = 0; k < Kr; ++k) c += hin_[k] * wsh[k*Nr + tid];
      if (mat == 2) c = c * sout_[tid] + hout_[tid];
    }
    bprep[(t*3 + mat)*128 + tid] = c;
  }

  ushort_t* wo = wprep + (size_t)(t*3 + mat) * WFRAGSZ;
  for (int ch = tid; ch < 1792; ch += 256) {            // 1792 chunks of 8 elems
    const int lane = ch & 63, ntkb = ch >> 6;
    const int nt = ntkb % 7, kb = ntkb / 7;
    const int n  = nt*16 + (lane & 15);
    const int k0 = kb*32 + (lane >> 4)*8;
    ushort_t tmp[8];
#pragma unroll
    for (int j = 0; j < 8; ++j) {
      const int k = k0 + j;
      float v = 0.f;
      if (n < Nr && k < Kr) {
        v = sin_[k] * wsh[k*Nr + n];
        if (mat == 2) v *= sout_[n];
      }
      tmp[j] = f2bf(v);
    }
    ushort4 lo; lo.x = tmp[0]; lo.y = tmp[1]; lo.z = tmp[2]; lo.w = tmp[3];
    ushort4 hi; hi.x = tmp[4]; hi.y = tmp[5]; hi.z = tmp[6]; hi.w = tmp[7];
    *(ushort4*)(wo + ch*8)     = lo;
    *(ushort4*)(wo + ch*8 + 4) = hi;
  }
}

// ---------------------------------------------------------------------------
// Layout transform: per path, stream the CONTIGUOUS 12KB X row + DW row into
// LDS, then emit:
//   xbt[t][b][128]  bf16, t=0..28 holds X[:, t+1, :] zero-padded to 128 cols
//   pbuf[tau][b][100] bf16, P = sigma_d * X[b, xt(tau), d] * DW[b, tau, d]
//     xt(0)=0, xt(tau)=min(tau,28)   (folds the epilogue's X/DW/sigma gather)
// All HBM reads contiguous; writes are >=256B slab chunks.
// ---------------------------------------------------------------------------
__global__ __launch_bounds__(256, 4)
void transpose_kernel(const float* __restrict__ X, const float* __restrict__ DW,
                      const float* __restrict__ sigmas,
                      ushort_t* __restrict__ xbt, ushort_t* __restrict__ pbuf)
{
  __shared__ __align__(16) float xs[3000];
  __shared__ __align__(16) float ds[3000];
  __shared__ float sig[128];
  const int tid = threadIdx.x;
  if (tid < 128) sig[tid] = (tid < 100) ? sigmas[tid] : 0.f;

  const int b0 = blockIdx.x * 8;
  for (int p = 0; p < 8; ++p) {
    const int b = b0 + p;
    __syncthreads();                       // xs/ds free (also covers sig on p=0)
    const float4* xr = (const float4*)(X  + (size_t)b * ROWSTR);
    const float4* dr = (const float4*)(DW + (size_t)b * ROWSTR);
    for (int i = tid; i < 750; i += 256) { // contiguous 12KB + 12KB
      ((float4*)xs)[i] = xr[i];
      ((float4*)ds)[i] = dr[i];
    }
    __syncthreads();

    // xbt: 29 slabs x 16 chunks of 16B
    for (int i = tid; i < 464; i += 256) {
      const int t0 = i >> 4, c = i & 15;
      s16x8 u;
#pragma unroll
      for (int j = 0; j < 8; ++j) {
        const int col = c*8 + j;
        const float v = (col < 100) ? xs[(t0+1)*100 + col] : 0.f;
        u[j] = (short)f2bf(v);
      }
      *(s16x8*)(xbt + ((size_t)t0*B_PATHS + b)*128 + c*8) = u;
    }
    // pbuf: 30 slabs x 25 chunks of 4 cols
    for (int i = tid; i < 750; i += 256) {
      const int tau = i / 25, g = i % 25;
      const int xt  = tau ? (tau < 29 ? tau : 28) : 0;
      const float* xp = xs + xt*100 + g*4;
      const float* dp = ds + tau*100 + g*4;
      const float* sp = sig + g*4;
      ushort4 u;
      u.x = f2bf(sp[0]*xp[0]*dp[0]);
      u.y = f2bf(sp[1]*xp[1]*dp[1]);
      u.z = f2bf(sp[2]*xp[2]*dp[2]);
      u.w = f2bf(sp[3]*xp[3]*dp[3]);
      *(ushort4*)(pbuf + ((size_t)tau*B_PATHS + b)*100 + g*4) = u;
    }
  }
}

// ---------------------------------------------------------------------------
// One MLP stage, M=16 rows per wave, act wave-private IN-PLACE; B-frags from
// LDS wbuf (shared by all 4 waves), ds_read_b128 conflict-free.
// ---------------------------------------------------------------------------
__device__ __forceinline__ void mlp_stage16(ushort_t* act, const ushort_t* wbuf,
                                            const float* __restrict__ biasg,
                                            int wrow, int lane, int lrow, int quad, bool relu)
{
  f32x4 acc[7];
  const f32x4 z4 = {0.f, 0.f, 0.f, 0.f};
#pragma unroll
  for (int nt = 0; nt < 7; ++nt) acc[nt] = z4;

  s16x8 a[4];
#pragma unroll
  for (int kb = 0; kb < 4; ++kb)
    a[kb] = *(const s16x8*)(act + (wrow + lrow)*LDK + kb*32 + quad*8);

#pragma unroll
  for (int kb = 0; kb < 4; ++kb) {
    s16x8 b[7];
#pragma unroll
    for (int nt = 0; nt < 7; ++nt)
      b[nt] = *(const s16x8*)(wbuf + ((kb*7 + nt)*64 + lane)*8);
#pragma unroll
    for (int nt = 0; nt < 7; ++nt)
      acc[nt] = __builtin_amdgcn_mfma_f32_16x16x32_bf16(a[kb], b[nt], acc[nt], 0, 0, 0);
  }

#pragma unroll
  for (int nt = 0; nt < 7; ++nt) {
    const int col = nt*16 + lrow;
    const float bv = biasg[col];
#pragma unroll
    for (int r = 0; r < 4; ++r) {
      float u = acc[nt][r] + bv;              // C/D layout: row=quad*4+r, col=lane&15
      if (relu) u = u > 0.f ? u : 0.f;
      act[(wrow + quad*4 + r)*LDK + col] = f2bf(u);
    }
  }
  // maintain zero pad cols [112,128) so next stage's K-sweep reads zeros
#pragma unroll
  for (int r = 0; r < 4; ++r)
    act[(wrow + quad*4 + r)*LDK + 112 + lrow] = 0;
}

// ---------------------------------------------------------------------------
// Fused subnet (R4 structure): block = (t, 64-row tile), 4 waves x 16 rows.
// Staging is a pure 16B bf16 copy from xbt[t] (contiguous 16KB per block);
// epilogue is a dot of streamed pbuf[t+1] (contiguous 12.8KB) with Z in LDS.
// W pipeline: global->reg early, reg->LDS late (T14), as verified in R4.
// ---------------------------------------------------------------------------
__global__ __launch_bounds__(256, 3)
void subnet_kernel(const ushort_t* __restrict__ xbt, const ushort_t* __restrict__ pbuf,
                   const ushort_t* __restrict__ wprep, const float* __restrict__ bprep,
                   float* __restrict__ sbuf)
{
  __shared__ __align__(16) ushort_t act[64*LDK];      // 17408 B
  __shared__ __align__(16) ushort_t wbuf[WFRAGSZ];    // 28672 B  (total 46080 B)

  const int tid  = threadIdx.x;
  const int t    = blockIdx.y;
  const int m0   = blockIdx.x * 64;
  const int lane = tid & 63;
  const int wrow = (tid >> 6) * 16;   // wave's private 16-row slice
  const int lrow = lane & 15, quad = lane >> 4;

  const ushort_t* wf = wprep + (size_t)(t*3) * WFRAGSZ;
  const float*    bg = bprep + (t*3) * 128;

  // ---- issue W0 loads (16B/thread x 7), latency overlaps X staging
  s16x8 wst[7];
#pragma unroll
  for (int j = 0; j < 7; ++j)
    wst[j] = *(const s16x8*)(wf + (j*256 + tid)*8);

  // ---- act <- xbt[t] tile: pure 16B copy, fully coalesced (16KB contiguous)
  {
    const ushort_t* xsrc = xbt + ((size_t)t*B_PATHS + m0)*128;
#pragma unroll
    for (int i = 0; i < 4; ++i) {
      const int j = tid + i*256, r = j >> 4, c = j & 15;
      *(s16x8*)(act + r*LDK + c*8) = *(const s16x8*)(xsrc + r*128 + c*8);
    }
  }

  // ---- write W0, barrier (covers act staging too)
#pragma unroll
  for (int j = 0; j < 7; ++j)
    *(s16x8*)(wbuf + (j*256 + tid)*8) = wst[j];
  __syncthreads();

  // ---- stage 0 (issue W1 first so its latency hides under compute)
#pragma unroll
  for (int j = 0; j < 7; ++j)
    wst[j] = *(const s16x8*)(wf + WFRAGSZ + (j*256 + tid)*8);
  mlp_stage16(act, wbuf, bg, wrow, lane, lrow, quad, true);
  __syncthreads();
#pragma unroll
  for (int j = 0; j < 7; ++j)
    *(s16x8*)(wbuf + (j*256 + tid)*8) = wst[j];
  __syncthreads();

  // ---- stage 1 (issue W2 first)
#pragma unroll
  for (int j = 0; j < 7; ++j)
    wst[j] = *(const s16x8*)(wf + 2*WFRAGSZ + (j*256 + tid)*8);
  mlp_stage16(act, wbuf, bg + 128, wrow, lane, lrow, quad, true);
  __syncthreads();
#pragma unroll
  for (int j = 0; j < 7; ++j)
    *(s16x8*)(wbuf + (j*256 + tid)*8) = wst[j];
  __syncthreads();

  // ---- stage 2: Z (bn3 folded)
  mlp_stage16(act, wbuf, bg + 256, wrow, lane, lrow, quad, false);

  // ---- epilogue: s_{t+1}[b] = sum_d P[t+1][b][d] * Z[b][d]
  // 4 lanes per row; Z rows are this wave's own (same-wave LDS order OK)
  {
    const int erow = wrow + (lane >> 2), epart = lane & 3;
    const int b    = m0 + erow;
    const ushort_t* pr = pbuf + ((size_t)(t+1)*B_PATHS + b)*100;
    float p = 0.f;
#pragma unroll
    for (int i = 0; i < 7; ++i) {
      const int g = epart + i*4;
      if (g < 25) {
        const ushort4 pu = *(const ushort4*)(pr + g*4);
        const ushort4 zu = *(const ushort4*)(act + erow*LDK + g*4);
        p += bf2f(pu.x)*bf2f(zu.x) + bf2f(pu.y)*bf2f(zu.y)
           + bf2f(pu.z)*bf2f(zu.z) + bf2f(pu.w)*bf2f(zu.w);
      }
    }
    p += __shfl_xor(p, 1, 64);
    p += __shfl_xor(p, 2, 64);
    if (epart == 0)
      sbuf[(size_t)(t+1)*B_PATHS + b] = p;
  }
}

// ---------------------------------------------------------------------------
// Y recursion, linearized:  y_final = y_init*G^30 + sum_tau s_tau * G^(29-tau)
// s_0 = sum_d P[0][b][d] * z_init[d]  (pbuf slab 0, contiguous).
// ---------------------------------------------------------------------------
__global__ __launch_bounds__(256)
void y_kernel(const ushort_t* __restrict__ pbuf, const float* __restrict__ y_init,
              const float* __restrict__ z_init, const float* __restrict__ sbuf,
              float* __restrict__ out)
{
  const int tid  = threadIdx.x;
  const int row  = tid >> 3, part = tid & 7;   // 32 paths per block
  const int b    = blockIdx.x * 32 + row;
  const ushort_t* pr = pbuf + (size_t)b*100;   // tau = 0 slab
  float p = 0.f;
#pragma unroll
  for (int g = part; g < 25; g += 8) {
    const ushort4 pu = *(const ushort4*)(pr + g*4);
    const float4  zv = *(const float4*)(z_init + g*4);
    p += bf2f(pu.x)*zv.x + bf2f(pu.y)*zv.y + bf2f(pu.z)*zv.z + bf2f(pu.w)*zv.w;
  }
  p += __shfl_xor(p, 1, 64);
  p += __shfl_xor(p, 2, 64);
  p += __shfl_xor(p, 4, 64);

  const float G = 1.f + R_C*DT_C;
  float ss = 0.f;
#pragma unroll
  for (int tau = 1 + part; tau < NSTEP; tau += 8)
    ss += sbuf[(size_t)tau*B_PATHS + b] * __powf(G, (float)(NSTEP - 1 - tau));
  ss += __shfl_xor(ss, 1, 64);
  ss += __shfl_xor(ss, 2, 64);
  ss += __shfl_xor(ss, 4, 64);

  if (part == 0)
    out[b] = y_init[0]*__powf(G, 30.f) + p*__powf(G, 29.f) + ss;
}

extern "C" void kernel_launch(void* const* d_in, const int* in_sizes, int n_in,
                              void* d_out, int out_size, void* d_ws, size_t ws_size,
                              hipStream_t stream) {
  const float* X      = (const float*)d_in[0];
  const float* DWs    = (const float*)d_in[1];
  const float* sigmas = (const float*)d_in[2];
  const float* y_init = (const float*)d_in[3];
  const float* z_init = (const float*)d_in[4];
  const float* W1     = (const float*)d_in[5];
  const float* W2     = (const float*)d_in[6];
  const float* W3     = (const float*)d_in[7];
  const float* bn[16];
  for (int i = 0; i < 16; ++i) bn[i] = (const float*)d_in[8 + i];

  char* ws = (char*)d_ws;
  ushort_t* wprep = (ushort_t*)(ws + WS_WPREP);
  float*    bprep = (float*)   (ws + WS_BPREP);
  float*    sbuf  = (float*)   (ws + WS_SBUF);
  ushort_t* xbt   = (ushort_t*)(ws + WS_XBT);
  ushort_t* pbuf  = (ushort_t*)(ws + WS_PBUF);
  float*    out   = (float*)d_out;

  prep_kernel<<<dim3(3, TT), 256, 0, stream>>>(
      W1, W2, W3,
      bn[0], bn[1], bn[2], bn[3],  bn[4], bn[5], bn[6], bn[7],
      bn[8], bn[9], bn[10], bn[11], bn[12], bn[13], bn[14], bn[15],
      wprep, bprep);
  transpose_kernel<<<dim3(B_PATHS/8), 256, 0, stream>>>(
      X, DWs, sigmas, xbt, pbuf);
  subnet_kernel<<<dim3(B_PATHS/64, TT), 256, 0, stream>>>(
      xbt, pbuf, wprep, bprep, sbuf);
  y_kernel<<<dim3(B_PATHS/32), 256, 0, stream>>>(
      pbuf, y_init, z_init, sbuf, out);
}